// Round 7
// baseline (99.779 us; speedup 1.0000x reference)
//
#include <hip/hip_runtime.h>
#include <stdint.h>

#define IN_F 2048
#define OUT_F 2048
#define N_ROWS 8192

// ---- GEMM geometry: 256x256 tile, BK=32, 8 waves (2Mx4N), 4-deep LDS,
// 4 phases/K-step with register prefetch-by-one-phase (asm ds_read).
#define BM 256
#define BN 256
#define BK 32
#define NT (IN_F / BK)             // 64 K-steps
#define TM_TILES (N_ROWS / BM)     // 32
#define TN_TILES (OUT_F / BN)      // 8
#define NWG (TM_TILES * TN_TILES)  // 256 == #CUs
#define TILE_SHORTS (BM * BK)      // 8192 shorts = 16 KiB
#define BUF_SHORTS (2 * TILE_SHORTS)  // A+B per buffer = 32 KiB

typedef __bf16 bf16x8 __attribute__((ext_vector_type(8)));
typedef float f32x4 __attribute__((ext_vector_type(4)));
typedef unsigned short ushortx8 __attribute__((ext_vector_type(8)));

__device__ __forceinline__ unsigned short f2bf(float f) {
  unsigned u = __builtin_bit_cast(unsigned, f);
  u += 0x7FFFu + ((u >> 16) & 1u);
  return (unsigned short)(u >> 16);
}

__device__ __forceinline__ void async16(void* lds, const void* g) {
  __builtin_amdgcn_global_load_lds(
      (const __attribute__((address_space(1))) void*)(uintptr_t)g,
      (__attribute__((address_space(3))) void*)(uint32_t)(uintptr_t)lds,
      16, 0, 0);
}

// inline-asm LDS read: invisible to SIInsertWaitcnts (no auto-drains);
// ordering/waits are manual (LGKM3_/fences per rule #18).
__device__ __forceinline__ bf16x8 dsr(uint32_t addr) {
  bf16x8 r;
  asm volatile("ds_read_b128 %0, %1" : "=v"(r) : "v"(addr));
  return r;
}

// ---- fused prep: blocks [0,8192) convert A fp32->bf16; [8192,10240) build Ht
__global__ __launch_bounds__(256) void k_prep(const float* __restrict__ A,
                                              unsigned short* __restrict__ Ab,
                                              const float* __restrict__ W,
                                              unsigned short* __restrict__ Ht) {
  const int bid = blockIdx.x;
  if (bid < 8192) {
    const size_t t = (size_t)bid * 256 + threadIdx.x;
    const float4* a4 = reinterpret_cast<const float4*>(A);
    float4 v0 = a4[2 * t];
    float4 v1 = a4[2 * t + 1];
    ushortx8 o;
    o[0] = f2bf(v0.x); o[1] = f2bf(v0.y); o[2] = f2bf(v0.z); o[3] = f2bf(v0.w);
    o[4] = f2bf(v1.x); o[5] = f2bf(v1.y); o[6] = f2bf(v1.z); o[7] = f2bf(v1.w);
    *reinterpret_cast<ushortx8*>(Ab + t * 8) = o;
  } else {
    // Ht[b][a] = H_perm[a][b] = s(q,c) * W[u][(q^c)*512 + v]
    const int t = (bid - 8192) * 256 + threadIdx.x;
    const int b = t >> 8;
    const int a0 = (t & 255) << 3;
    const int c = b & 3, v = b >> 2;
    ushortx8 o;
#pragma unroll
    for (int e = 0; e < 8; ++e) {
      const int a = a0 + e;
      const int q = a & 3, u = a >> 2;
      float w = W[(size_t)u * OUT_F + ((q ^ c) << 9) + v];
      if ((0x284E >> ((q << 2) | c)) & 1) w = -w;
      o[e] = f2bf(w);
    }
    *reinterpret_cast<ushortx8*>(Ht + (size_t)b * IN_F + a0) = o;
  }
}

// ---- main GEMM: C = A(bf16) @ Ht^T + bias ----
__global__ __launch_bounds__(512, 2) void k_gemm(const unsigned short* __restrict__ A,
                                                 const unsigned short* __restrict__ Bt,
                                                 const float* __restrict__ bias,
                                                 float* __restrict__ C) {
  __shared__ __align__(16) unsigned short lds[4 * BUF_SHORTS];  // 128 KiB

  const int tid = threadIdx.x;
  const int lane = tid & 63;
  const int w = tid >> 6;   // wave 0..7
  const int wm = w >> 2;    // 0..1 -> rows wm*128..+128
  const int wn = w & 3;     // 0..3 -> cols wn*64..+64
  const int fr = lane & 15;
  const int g = lane >> 4;  // k-group 0..3 (8 bf16 each)

  // XCD-bijective swizzle: 256 wgs, 32 contiguous tiles per XCD
  const int wg = blockIdx.x;
  const int swz = (wg & 7) * (NWG >> 3) + (wg >> 3);
  const int tm = swz >> 3;
  const int tn = swz & 7;
  const int row0 = tm * BM, col0 = tn * BN;

  // ---- staging (r2-verified): chunk t in [0,1024): row r=t>>2, slot s=t&3;
  // write-side swizzle: slot s holds k-group ga = s ^ ((r>>1)&3)
  // (pre-swizzled GLOBAL source, linear LDS dest).
  const unsigned short* srcA0;
  const unsigned short* srcA1;
  const unsigned short* srcB0;
  const unsigned short* srcB1;
  int tOff0, tOff1;
  {
    const int t0 = w * 128 + lane, t1 = t0 + 64;
    const int r0_ = t0 >> 2, s0_ = t0 & 3, ga0 = s0_ ^ ((r0_ >> 1) & 3);
    const int r1_ = t1 >> 2, s1_ = t1 & 3, ga1 = s1_ ^ ((r1_ >> 1) & 3);
    srcA0 = A + (size_t)(row0 + r0_) * IN_F + ga0 * 8;
    srcA1 = A + (size_t)(row0 + r1_) * IN_F + ga1 * 8;
    srcB0 = Bt + (size_t)(col0 + r0_) * IN_F + ga0 * 8;
    srcB1 = Bt + (size_t)(col0 + r1_) * IN_F + ga1 * 8;
    tOff0 = t0 * 8;
    tOff1 = t1 * 8;
  }

#define STAGE(T)                                              \
  do {                                                        \
    unsigned short* base_ = &lds[((T) & 3) * BUF_SHORTS];     \
    const int ko_ = (T) * BK;                                 \
    async16(base_ + tOff0, srcA0 + ko_);                      \
    async16(base_ + tOff1, srcA1 + ko_);                      \
    async16(base_ + TILE_SHORTS + tOff0, srcB0 + ko_);        \
    async16(base_ + TILE_SHORTS + tOff1, srcB1 + ko_);        \
  } while (0)

  // ---- fragment read BYTE offsets; read-side swizzle matches write side
  const uint32_t lb = (uint32_t)(uintptr_t)&lds[0];
  uint32_t aoff[8], boff[4];
#pragma unroll
  for (int m = 0; m < 8; ++m) {
    const int r = wm * 128 + m * 16 + fr;
    aoff[m] = (uint32_t)((r * BK + ((g ^ ((r >> 1) & 3)) << 3)) * 2);
  }
#pragma unroll
  for (int n = 0; n < 4; ++n) {
    const int r = wn * 64 + n * 16 + fr;
    boff[n] = (uint32_t)(TILE_SHORTS * 2 + (r * BK + ((g ^ ((r >> 1) & 3)) << 3)) * 2);
  }

  f32x4 acc[8][4] = {};
  bf16x8 aP[2], aQ[2], bX[4], bY[4];

#define MFMA_(a_, b_, c_) __builtin_amdgcn_mfma_f32_16x16x32_bf16(a_, b_, c_, 0, 0, 0)
#define FENCE_ __builtin_amdgcn_sched_barrier(0)
#define SBAR_ asm volatile("s_barrier" ::: "memory")
#define LGKM3_ asm volatile("s_waitcnt lgkmcnt(3)")
#define LGKM0_ asm volatile("s_waitcnt lgkmcnt(0)" ::: "memory")
#define VM0_ asm volatile("s_waitcnt vmcnt(0)" ::: "memory")
#define VM4_ asm volatile("s_waitcnt vmcnt(4)" ::: "memory")

#define MM8(M0, AP_, B_)                                          \
  __builtin_amdgcn_s_setprio(1);                                  \
  acc[(M0)][0] = MFMA_(AP_[0], B_[0], acc[(M0)][0]);              \
  acc[(M0) + 1][0] = MFMA_(AP_[1], B_[0], acc[(M0) + 1][0]);      \
  acc[(M0)][1] = MFMA_(AP_[0], B_[1], acc[(M0)][1]);              \
  acc[(M0) + 1][1] = MFMA_(AP_[1], B_[1], acc[(M0) + 1][1]);      \
  acc[(M0)][2] = MFMA_(AP_[0], B_[2], acc[(M0)][2]);              \
  acc[(M0) + 1][2] = MFMA_(AP_[1], B_[2], acc[(M0) + 1][2]);      \
  acc[(M0)][3] = MFMA_(AP_[0], B_[3], acc[(M0)][3]);              \
  acc[(M0) + 1][3] = MFMA_(AP_[1], B_[3], acc[(M0) + 1][3]);      \
  __builtin_amdgcn_s_setprio(0)

  // One K-step = 4 phases. MFMA(phase p) consumes frags read in phase p-1
  // (counted lgkmcnt(3) = just-issued reads). One barrier+vmcnt per K-step.
#define KSTEP(T, BC_, BN_)                                        \
  /* ph0 */                                                       \
  aQ[0] = dsr(lb + (((T) & 3) << 15) + aoff[2]);                  \
  aQ[1] = dsr(lb + (((T) & 3) << 15) + aoff[3]);                  \
  BN_[0] = dsr(lb + ((((T) + 1) & 3) << 15) + boff[0]);           \
  FENCE_; LGKM3_; FENCE_;                                         \
  MM8(0, aP, BC_); FENCE_;                                        \
  /* ph1 */                                                       \
  aP[0] = dsr(lb + (((T) & 3) << 15) + aoff[4]);                  \
  aP[1] = dsr(lb + (((T) & 3) << 15) + aoff[5]);                  \
  BN_[1] = dsr(lb + ((((T) + 1) & 3) << 15) + boff[1]);           \
  FENCE_; LGKM3_; FENCE_;                                         \
  MM8(2, aQ, BC_); FENCE_;                                        \
  /* ph2 */                                                       \
  aQ[0] = dsr(lb + (((T) & 3) << 15) + aoff[6]);                  \
  aQ[1] = dsr(lb + (((T) & 3) << 15) + aoff[7]);                  \
  BN_[2] = dsr(lb + ((((T) + 1) & 3) << 15) + boff[2]);           \
  FENCE_; LGKM3_; FENCE_;                                         \
  MM8(4, aP, BC_); FENCE_;                                        \
  /* ph3: all reads of buf[(T+3)&3]'s old data retired >=1 barrier ago; */ \
  /* vmcnt(0): outstanding stage is 4 phases old (benign drain). */ \
  VM0_; SBAR_; FENCE_;                                            \
  aP[0] = dsr(lb + ((((T) + 1) & 3) << 15) + aoff[0]);            \
  aP[1] = dsr(lb + ((((T) + 1) & 3) << 15) + aoff[1]);            \
  BN_[3] = dsr(lb + ((((T) + 1) & 3) << 15) + boff[3]);           \
  FENCE_;                                                         \
  if ((T) + 3 < NT) STAGE((T) + 3);                               \
  FENCE_; LGKM3_; FENCE_;                                         \
  MM8(6, aQ, BC_); FENCE_

  // ---- prologue: 3 tiles staged; tiles 0,1 landed before first reads ----
  STAGE(0);
  STAGE(1);
  STAGE(2);
  VM4_; SBAR_; FENCE_;
  aP[0] = dsr(lb + aoff[0]);
  aP[1] = dsr(lb + aoff[1]);
  bX[0] = dsr(lb + boff[0]);
  bX[1] = dsr(lb + boff[1]);
  bX[2] = dsr(lb + boff[2]);
  bX[3] = dsr(lb + boff[3]);
  FENCE_;

#pragma unroll 1
  for (int t = 0; t < NT; t += 2) {
    KSTEP(t, bX, bY);      // consumes B(t)=bX, prefetches B(t+1)->bY
    KSTEP(t + 1, bY, bX);  // consumes bY, prefetches bX
  }

  LGKM0_; FENCE_;
  // keep last (dead) prefetch destinations live until after the drain, so
  // the register allocator can't reuse them while DS returns are pending.
  asm volatile("" ::"v"(aP[0]), "v"(aP[1]), "v"(bX[0]), "v"(bX[1]),
               "v"(bX[2]), "v"(bX[3]));

#undef KSTEP
#undef MM8
#undef STAGE

  // ---- epilogue: C/D layout col=lane&15, row=(lane>>4)*4+reg ----
  const int g4 = g << 2;
  float bv[4];
#pragma unroll
  for (int n = 0; n < 4; ++n) bv[n] = bias[col0 + wn * 64 + n * 16 + fr];
#pragma unroll
  for (int m = 0; m < 8; ++m) {
#pragma unroll
    for (int e = 0; e < 4; ++e) {
      const int row = row0 + wm * 128 + m * 16 + g4 + e;
      float* cp = C + (size_t)row * OUT_F + col0 + wn * 64 + fr;
#pragma unroll
      for (int n = 0; n < 4; ++n) cp[n * 16] = acc[m][n][e] + bv[n];
    }
  }
}

// ---- fallback if workspace too small: naive fp32 ----
__global__ __launch_bounds__(256) void k_naive(const float* __restrict__ A,
                                               const float* __restrict__ W,
                                               const float* __restrict__ bias,
                                               float* __restrict__ C) {
  const int idx = blockIdx.x * 256 + threadIdx.x;
  const int m = idx >> 11;
  const int b = idx & (OUT_F - 1);
  const int c = b & 3, v = b >> 2;
  float acc = 0.f;
  const float* arow = A + (size_t)m * IN_F;
  for (int a = 0; a < IN_F; ++a) {
    const int q = a & 3, u = a >> 2;
    float h = W[(size_t)u * OUT_F + ((q ^ c) << 9) + v];
    if ((0x284E >> ((q << 2) | c)) & 1) h = -h;
    acc += arow[a] * h;
  }
  C[idx] = acc + bias[b];
}

extern "C" void kernel_launch(void* const* d_in, const int* in_sizes, int n_in,
                              void* d_out, int out_size, void* d_ws, size_t ws_size,
                              hipStream_t stream) {
  (void)in_sizes; (void)n_in; (void)out_size;
  const float* inp  = (const float*)d_in[0];
  const float* w    = (const float*)d_in[1];
  const float* bias = (const float*)d_in[2];
  float* out = (float*)d_out;

  const size_t needA = (size_t)N_ROWS * IN_F * sizeof(unsigned short);  // 32 MiB
  const size_t needH = (size_t)IN_F * OUT_F * sizeof(unsigned short);   //  8 MiB
  if (ws_size < needA + needH) {
    k_naive<<<(N_ROWS * OUT_F) / 256, 256, 0, stream>>>(inp, w, bias, out);
    return;
  }

  unsigned short* Ab = (unsigned short*)d_ws;
  unsigned short* Ht = Ab + (size_t)N_ROWS * IN_F;

  k_prep<<<8192 + 2048, 256, 0, stream>>>(inp, Ab, w, Ht);
  k_gemm<<<NWG, 512, 0, stream>>>(Ab, Ht, bias, out);
}